// Round 4
// baseline (27.760 us; speedup 1.0000x reference)
//
#include <hip/hip_runtime.h>

#define B_ 8
#define LQ_ 64
#define LK_ 256
#define E_ 128
#define H_ 4
#define D_ 32
#define NH_ 128
#define EK_ 32

// ---------------------------------------------------------------------------
// Round-8: R4 structure (proven 17.3us) + key-gather elimination.
// Evidence (R5/R6/R7): time tracks per-CU memory-transaction count only.
// R4's phase-5 key gather = 8192 L1 line-touches at 25% line use (64 distinct
// rows per wave-instr). This round:
//  - key[b] (128 KB) staged to LDS: coalesced chunk reads = 2048 full-line
//    touches (the floor), reg-staged, ds_write to XOR-swizzled row-major
//    kt[k][j^(k&7)] (f4 units). Write side (lanes vary j) and read side
//    (lanes vary k) are both exactly bank-even -> conflict-free.
//  - phase 5 remap: 2 rows/lane x e-quarter (same 16xf4 key regs, same
//    512 FMA/lane) -> each g broadcast feeds 2 row-dots: 64 instead of 128
//    ds_read_b128 per lane. spart = 4 quarters; phase 6 combines 4.
//  - 136 KB dynamic LDS; spart/e_lds/nump/denp alias kt after phase 5a
//    (barrier-separated).
// Everything else (phases 1-4, 6-11 logic, mappings) R4-exact.
// ---------------------------------------------------------------------------
__global__ __launch_bounds__(512) void fused_attn_kernel(
    const float* __restrict__ query, const float* __restrict__ key,
    const float* __restrict__ value, const int* __restrict__ mask,
    const float* __restrict__ Wq, const float* __restrict__ bq,
    const float* __restrict__ Wk,
    const float* __restrict__ Wo, const float* __restrict__ bo,
    float* __restrict__ out)
{
    const int blk = blockIdx.x;       // 256 blocks
    const int b  = blk >> 5;
    const int q0 = (blk & 31) * 2;
    const int t  = threadIdx.x;

    extern __shared__ float dyn[];    // 34816 floats = 136 KB
    float* qrow  = dyn;               // 256            (phases 1-2)
    float* qpart = dyn + 256;         // 512            (2-3)
    float* qp    = dyn + 768;         // 256            (3-4)
    float* g     = dyn + 1024;        // 1024           (4-5)
    float* kt    = dyn + 2048;        // 32768 = 128KB  (2.5-5a)
    float* spart = dyn + 2048;        // 8192 (alias kt)(5b-6)
    float* e_lds = dyn + 10240;       // 2048           (7-8)
    float* nump  = dyn + 12288;       // 4096           (8-9)
    float* denp  = dyn + 16384;       // 4096           (8-9)
    float* x     = dyn + 20480;       // 256            (9-10)
    float* opart = dyn + 20736;       // 1024           (10-11)

    // ---- 0a. issue key staging reads: 16 f4/thread, fully coalesced ----
    // chunk n = i*512 + t: each wave-instr reads 64 consecutive f4 = 16 full
    // 64B lines. Whole key batch = 2048 line-touches (minimum possible).
    float4 st[16];
    {
        const float4* kb4 =
            reinterpret_cast<const float4*>(key + (size_t)b * LK_ * E_);
        #pragma unroll
        for (int i = 0; i < 16; ++i) st[i] = kb4[i * 512 + t];
    }

    // ---- 0b. value/mask prefetch into regs (consumed phase 8) ----
    const int d  = t & 31;
    const int kg = t >> 5;            // 16 k-groups of 16
    float vv[16], mfv[16];
    {
        const float* vb = value + ((size_t)(b * LK_) + kg * 16) * D_ + d;
        const int*   mb = mask  + ((size_t)(b * LK_) + kg * 16) * D_ + d;
        #pragma unroll
        for (int j = 0; j < 16; ++j) {
            vv[j]  = vb[j * D_];
            mfv[j] = (float)mb[j * D_];
        }
    }

    // ---- 1. two query rows -> LDS ----
    if (t < 64) {
        reinterpret_cast<float4*>(qrow)[t] =
            reinterpret_cast<const float4*>(query + ((size_t)(b * LQ_) + q0) * E_)[t];
    }
    __syncthreads();

    // ---- 2. qp partials: thread (col, z=(eh<<1)|r), f4 qrow broadcasts ----
    {
        const int col = t & 127;
        const int z   = t >> 7;
        const int r   = z & 1;
        const int eh  = z >> 1;
        const float4* qr4 = reinterpret_cast<const float4*>(qrow + r * 128 + eh * 64);
        const float* wq = Wq + (size_t)(eh * 64) * E_ + col;
        float acc = 0.0f;
        #pragma unroll
        for (int j = 0; j < 16; ++j) {
            float4 qv = qr4[j];
            acc = fmaf(qv.x, wq[(size_t)(j * 4 + 0) * E_], acc);
            acc = fmaf(qv.y, wq[(size_t)(j * 4 + 1) * E_], acc);
            acc = fmaf(qv.z, wq[(size_t)(j * 4 + 2) * E_], acc);
            acc = fmaf(qv.w, wq[(size_t)(j * 4 + 3) * E_], acc);
        }
        qpart[z * 128 + col] = acc;
    }
    // ---- 2.5. key -> kt (XOR-swizzled). Phase-2's Wq consumption already
    // forced vmcnt past the staging loads (in-order), so no extra stall.
    // Write banks: lanes vary j (uniform), XOR by row harmless -> even. ----
    {
        float4* kt4 = reinterpret_cast<float4*>(kt);
        #pragma unroll
        for (int i = 0; i < 16; ++i) {
            const int n  = i * 512 + t;
            const int kk = n >> 5;
            const int jj = n & 31;
            kt4[kk * 32 + (jj ^ (kk & 7))] = st[i];
        }
    }
    __syncthreads();

    // ---- 3. qp finalize ----
    if (t < 256) {
        const int col = t & 127, r = t >> 7;
        qp[r * 128 + col] =
            qpart[r * 128 + col] + qpart[(2 + r) * 128 + col] + bq[col];
    }
    __syncthreads();

    // ---- 4. g[rh][e]: Wk regs reused across the two rows (R4 exact) ----
    {
        const float inv_sqrt_ek = 0.17677669529663687f;  // 1/sqrt(32)
        const int e = t >> 2;
        const int p = t & 3;       // head
        const float4* wk4 = reinterpret_cast<const float4*>(Wk + (size_t)e * E_ + p * EK_);
        float4 w[8];
        #pragma unroll
        for (int j = 0; j < 8; ++j) w[j] = wk4[j];
        #pragma unroll
        for (int r = 0; r < 2; ++r) {
            const float4* qp4 = reinterpret_cast<const float4*>(qp + r * 128 + p * EK_);
            float acc = 0.0f;
            #pragma unroll
            for (int j = 0; j < 8; ++j) {
                float4 pv = qp4[j];
                acc = fmaf(w[j].x, pv.x, acc);
                acc = fmaf(w[j].y, pv.y, acc);
                acc = fmaf(w[j].z, pv.z, acc);
                acc = fmaf(w[j].w, pv.w, acc);
            }
            g[(r * 4 + p) * 128 + e] = acc * inv_sqrt_ek;
        }
    }
    __syncthreads();

    // ---- 5a. score partials: 2 rows/lane (k5, k5+128) x e-quarter eq5 ----
    // kt reads: lanes vary k -> XOR spreads bank groups evenly (conflict-
    // free). g reads: lane-uniform broadcasts, each feeds TWO row-dots.
    const int k5  = t & 127;
    const int eq5 = t >> 7;           // 0..3
    float acc0[8] = {0.f, 0.f, 0.f, 0.f, 0.f, 0.f, 0.f, 0.f};
    float acc1[8] = {0.f, 0.f, 0.f, 0.f, 0.f, 0.f, 0.f, 0.f};
    {
        const int xr = k5 & 7;        // == (k5+128)&7
        const float4* kt4 = reinterpret_cast<const float4*>(kt);
        const float4* g4  = reinterpret_cast<const float4*>(g);
        #pragma unroll
        for (int j = 0; j < 8; ++j) {
            const int jj = eq5 * 8 + j;
            const float4 kv0 = kt4[k5 * 32 + (jj ^ xr)];
            const float4 kv1 = kt4[(k5 + 128) * 32 + (jj ^ xr)];
            #pragma unroll
            for (int rh = 0; rh < 8; ++rh) {
                const float4 gg = g4[rh * 32 + jj];
                acc0[rh] = fmaf(kv0.x, gg.x, acc0[rh]);
                acc0[rh] = fmaf(kv0.y, gg.y, acc0[rh]);
                acc0[rh] = fmaf(kv0.z, gg.z, acc0[rh]);
                acc0[rh] = fmaf(kv0.w, gg.w, acc0[rh]);
                acc1[rh] = fmaf(kv1.x, gg.x, acc1[rh]);
                acc1[rh] = fmaf(kv1.y, gg.y, acc1[rh]);
                acc1[rh] = fmaf(kv1.z, gg.z, acc1[rh]);
                acc1[rh] = fmaf(kv1.w, gg.w, acc1[rh]);
            }
        }
    }
    __syncthreads();                  // kt dead -> spart may alias it

    // ---- 5b. write spart (lanes consecutive k -> conflict-free) ----
    #pragma unroll
    for (int rh = 0; rh < 8; ++rh) {
        spart[(eq5 * 8 + rh) * 256 + k5]       = acc0[rh];
        spart[(eq5 * 8 + rh) * 256 + k5 + 128] = acc1[rh];
    }
    __syncthreads();

    // ---- 6+7. combine 4 e-quarters + max + exp (wave w owns rh=w) ----
    {
        const int w = t >> 6;        // rh
        const int l = t & 63;        // k-quad
        const float4* sp4 = reinterpret_cast<const float4*>(spart);
        float4 s0 = sp4[w * 64 + l];
        #pragma unroll
        for (int eq = 1; eq < 4; ++eq) {
            float4 s1 = sp4[(eq * 8 + w) * 64 + l];
            s0.x += s1.x; s0.y += s1.y; s0.z += s1.z; s0.w += s1.w;
        }
        float m = fmaxf(fmaxf(s0.x, s0.y), fmaxf(s0.z, s0.w));
        #pragma unroll
        for (int off = 32; off; off >>= 1)
            m = fmaxf(m, __shfl_xor(m, off));
        float4 e;
        e.x = __expf(s0.x - m); e.y = __expf(s0.y - m);
        e.z = __expf(s0.z - m); e.w = __expf(s0.w - m);
        *reinterpret_cast<float4*>(&e_lds[w * LK_ + l * 4]) = e;
    }
    __syncthreads();

    // ---- 8. masked num/den over k: f4 e_lds reads (2-way = free) ----
    {
        float num[8] = {0.f, 0.f, 0.f, 0.f, 0.f, 0.f, 0.f, 0.f};
        float den[8] = {0.f, 0.f, 0.f, 0.f, 0.f, 0.f, 0.f, 0.f};
        #pragma unroll
        for (int jq = 0; jq < 4; ++jq) {
            const float4 mv4 = make_float4(mfv[jq*4+0]*vv[jq*4+0], mfv[jq*4+1]*vv[jq*4+1],
                                           mfv[jq*4+2]*vv[jq*4+2], mfv[jq*4+3]*vv[jq*4+3]);
            const float4 mf4 = make_float4(mfv[jq*4+0], mfv[jq*4+1],
                                           mfv[jq*4+2], mfv[jq*4+3]);
            #pragma unroll
            for (int rh = 0; rh < 8; ++rh) {
                float4 ev = *reinterpret_cast<const float4*>(
                    &e_lds[rh * LK_ + kg * 16 + jq * 4]);
                num[rh] = fmaf(ev.x, mv4.x, num[rh]);
                num[rh] = fmaf(ev.y, mv4.y, num[rh]);
                num[rh] = fmaf(ev.z, mv4.z, num[rh]);
                num[rh] = fmaf(ev.w, mv4.w, num[rh]);
                den[rh] = fmaf(ev.x, mf4.x, den[rh]);
                den[rh] = fmaf(ev.y, mf4.y, den[rh]);
                den[rh] = fmaf(ev.z, mf4.z, den[rh]);
                den[rh] = fmaf(ev.w, mf4.w, den[rh]);
            }
        }
        #pragma unroll
        for (int rh = 0; rh < 8; ++rh) {
            nump[(kg * 8 + rh) * 32 + d] = num[rh];
            denp[(kg * 8 + rh) * 32 + d] = den[rh];
        }
    }
    __syncthreads();

    // ---- 9. x = num/den ----
    if (t < 256) {
        const int rh = t >> 5, dd = t & 31;
        float n = 0.f, dn = 0.f;
        #pragma unroll
        for (int k2 = 0; k2 < 16; ++k2) {
            n  += nump[(k2 * 8 + rh) * 32 + dd];
            dn += denp[(k2 * 8 + rh) * 32 + dd];
        }
        x[(rh >> 2) * 128 + (rh & 3) * 32 + dd] = n / dn;
    }
    __syncthreads();

    // ---- 10. out projection, f4 x broadcasts, Wo read once (r inside) ----
    {
        const int col = t & 127;
        const int eq  = t >> 7;      // 0..3
        const int c0  = eq * 32;
        const float* wo = Wo + (size_t)c0 * NH_ + col;
        const float4* x40 = reinterpret_cast<const float4*>(x + c0);
        const float4* x41 = reinterpret_cast<const float4*>(x + 128 + c0);
        float acc0o = 0.f, acc1o = 0.f;
        #pragma unroll
        for (int j = 0; j < 8; ++j) {
            float4 xv0 = x40[j];
            float4 xv1 = x41[j];
            float w0 = wo[(size_t)(j * 4 + 0) * NH_];
            float w1 = wo[(size_t)(j * 4 + 1) * NH_];
            float w2 = wo[(size_t)(j * 4 + 2) * NH_];
            float w3 = wo[(size_t)(j * 4 + 3) * NH_];
            acc0o = fmaf(xv0.x, w0, acc0o); acc1o = fmaf(xv1.x, w0, acc1o);
            acc0o = fmaf(xv0.y, w1, acc0o); acc1o = fmaf(xv1.y, w1, acc1o);
            acc0o = fmaf(xv0.z, w2, acc0o); acc1o = fmaf(xv1.z, w2, acc1o);
            acc0o = fmaf(xv0.w, w3, acc0o); acc1o = fmaf(xv1.w, w3, acc1o);
        }
        opart[(eq * 2 + 0) * 128 + col] = acc0o;
        opart[(eq * 2 + 1) * 128 + col] = acc1o;
    }
    __syncthreads();

    // ---- 11. finalize + store both rows ----
    if (t < 256) {
        const int col = t & 127, r = t >> 7;
        float s = bo[col];
        #pragma unroll
        for (int eq = 0; eq < 4; ++eq)
            s += opart[(eq * 2 + r) * 128 + col];
        out[((size_t)(b * LQ_) + q0 + r) * NH_ + col] = s;
    }
}

extern "C" void kernel_launch(void* const* d_in, const int* in_sizes, int n_in,
                              void* d_out, int out_size, void* d_ws, size_t ws_size,
                              hipStream_t stream) {
    const float* query = (const float*)d_in[0];
    const float* key   = (const float*)d_in[1];
    const float* value = (const float*)d_in[2];
    const int*   mask  = (const int*)d_in[3];
    const float* Wq    = (const float*)d_in[4];
    const float* bq    = (const float*)d_in[5];
    const float* Wk    = (const float*)d_in[6];
    // d_in[7] = bk: k-constant in scores -> cancels in softmax -> unused
    const float* Wo    = (const float*)d_in[8];
    const float* bo    = (const float*)d_in[9];
    float* out = (float*)d_out;

    const size_t lds_bytes = 34816 * sizeof(float);   // 136 KB
    static bool attr_set = false;
    if (!attr_set) {
        hipFuncSetAttribute(reinterpret_cast<const void*>(fused_attn_kernel),
                            hipFuncAttributeMaxDynamicSharedMemorySize,
                            (int)lds_bytes);
        attr_set = true;
    }

    fused_attn_kernel<<<B_ * (LQ_ / 2), 512, lds_bytes, stream>>>(
        query, key, value, mask, Wq, bq, Wk, Wo, bo, out);
}

// Round 5
// 16.317 us; speedup vs baseline: 1.7013x; 1.7013x over previous
//
#include <hip/hip_runtime.h>

#define B_ 8
#define LQ_ 64
#define LK_ 256
#define E_ 128
#define H_ 4
#define D_ 32
#define NH_ 128
#define EK_ 32

// ---------------------------------------------------------------------------
// Round-9: R8's staging thesis, spill-free.
// R8 failed on register spills (VGPR_Count=68, WRITE_SIZE=33MB scratch).
// This round:
//  - key[b] staged HBM->LDS via __builtin_amdgcn_global_load_lds (width 16):
//    no VGPR staging at all. LDS dest is linear (HW: base+lane*16); the
//    conflict-free layout comes from PRE-SWIZZLING the per-lane GLOBAL source
//    (lane filling slot k*32+p reads key[k][p^(k&7)]). Each wave instr still
//    covers 2 full key rows = 16 full 64B lines -> 2048 full-line touches
//    for the whole batch (vs 8192 quarter-used in the R4 gather).
//  - phase 5: 2 rows/lane x e-quarter (g broadcasts halved, 16 acc VGPRs).
//    kt reads kt4[k*32+(jj^(k&7))]: XOR spreads lanes' 16B chunks evenly
//    across all 32 banks -> conflict-free.
//  - phase 2: both q-rows per thread -> Wq touched once (1024 full lines).
//  - __launch_bounds__(512,2): VGPR cap 256, live set ~120 -> no spills.
//  - 138 KB dynamic LDS; spart/e_lds/nump/denp/x/opart alias kt after 5a.
// Everything else R4-exact.
// ---------------------------------------------------------------------------
__global__ __launch_bounds__(512, 2) void fused_attn_kernel(
    const float* __restrict__ query, const float* __restrict__ key,
    const float* __restrict__ value, const int* __restrict__ mask,
    const float* __restrict__ Wq, const float* __restrict__ bq,
    const float* __restrict__ Wk,
    const float* __restrict__ Wo, const float* __restrict__ bo,
    float* __restrict__ out)
{
    const int blk = blockIdx.x;       // 256 blocks
    const int b  = blk >> 5;
    const int q0 = (blk & 31) * 2;
    const int t  = threadIdx.x;

    extern __shared__ float dyn[];    // 35328 floats = 138 KB
    float* qrow  = dyn;               // 256            (phases 1-2)
    float* qpart = dyn + 256;         // 1024           (2-3)
    float* qp    = dyn + 1280;        // 256            (3-4)
    float* g     = dyn + 1536;        // 1024           (4-5)
    float* kt    = dyn + 2560;        // 32768 = 128KB  (0-5a)
    float* spart = dyn + 2560;        // 8192  (alias)  (5b-6)
    float* e_lds = dyn + 10752;       // 2048  (alias)  (7-8)
    float* nump  = dyn + 12800;       // 4096  (alias)  (8-9)
    float* denp  = dyn + 16896;       // 4096  (alias)  (8-9)
    float* x     = dyn + 20992;       // 256   (alias)  (9-10)
    float* opart = dyn + 21248;       // 1024  (alias)  (10-11)

    // ---- 0a. key -> kt via global_load_lds, pre-swizzled global source ----
    // slot = i*512 + t (f4 units); k = slot>>5, p = slot&31.
    // kt_linear[slot] <- key[k][p ^ (k&7)]  (f4 elements)
    {
        const float4* kb4 =
            reinterpret_cast<const float4*>(key + (size_t)b * LK_ * E_);
        #pragma unroll
        for (int i = 0; i < 16; ++i) {
            const int slot = i * 512 + t;
            const int k  = slot >> 5;
            const int p  = slot & 31;
            const float4* src = kb4 + (k * 32 + (p ^ (k & 7)));
            __builtin_amdgcn_global_load_lds(
                (const __attribute__((address_space(1))) void*)src,
                (__attribute__((address_space(3))) void*)(&kt[slot * 4]),
                16, 0, 0);
        }
    }

    // ---- 0b. value/mask prefetch into regs (consumed phase 8) ----
    const int d  = t & 31;
    const int kg = t >> 5;            // 16 k-groups of 16
    float vv[16], mfv[16];
    {
        const float* vb = value + ((size_t)(b * LK_) + kg * 16) * D_ + d;
        const int*   mb = mask  + ((size_t)(b * LK_) + kg * 16) * D_ + d;
        #pragma unroll
        for (int j = 0; j < 16; ++j) {
            vv[j]  = vb[j * D_];
            mfv[j] = (float)mb[j * D_];
        }
    }

    // ---- 0c. Wk fragment hoist (phase-4 mapping: e=t>>2, p=t&3) ----
    const int e4 = t >> 2, p4 = t & 3;
    float4 wkr[8];
    {
        const float4* wk4 =
            reinterpret_cast<const float4*>(Wk + (size_t)e4 * E_ + p4 * EK_);
        #pragma unroll
        for (int j = 0; j < 8; ++j) wkr[j] = wk4[j];
    }

    // ---- 1. two query rows -> LDS ----
    if (t < 64) {
        reinterpret_cast<float4*>(qrow)[t] =
            reinterpret_cast<const float4*>(query + ((size_t)(b * LQ_) + q0) * E_)[t];
    }
    __syncthreads();

    // ---- 2. qp partials: thread (col, slab=t>>7); BOTH rows per thread ----
    // Wq element read exactly once per block (1024 full-line touches).
    {
        const int col  = t & 127;
        const int slab = t >> 7;      // 0..3 : 32-row slab of Wq
        const float4* qr0 = reinterpret_cast<const float4*>(qrow + slab * 32);
        const float4* qr1 = reinterpret_cast<const float4*>(qrow + 128 + slab * 32);
        const float* wq = Wq + (size_t)(slab * 32) * E_ + col;
        float acc0 = 0.0f, acc1 = 0.0f;
        #pragma unroll
        for (int j = 0; j < 8; ++j) {
            float4 q0v = qr0[j];
            float4 q1v = qr1[j];
            float w0 = wq[(size_t)(j * 4 + 0) * E_];
            float w1 = wq[(size_t)(j * 4 + 1) * E_];
            float w2 = wq[(size_t)(j * 4 + 2) * E_];
            float w3 = wq[(size_t)(j * 4 + 3) * E_];
            acc0 = fmaf(q0v.x, w0, acc0); acc1 = fmaf(q1v.x, w0, acc1);
            acc0 = fmaf(q0v.y, w1, acc0); acc1 = fmaf(q1v.y, w1, acc1);
            acc0 = fmaf(q0v.z, w2, acc0); acc1 = fmaf(q1v.z, w2, acc1);
            acc0 = fmaf(q0v.w, w3, acc0); acc1 = fmaf(q1v.w, w3, acc1);
        }
        qpart[(slab * 2 + 0) * 128 + col] = acc0;
        qpart[(slab * 2 + 1) * 128 + col] = acc1;
    }
    __syncthreads();

    // ---- 3. qp finalize ----
    if (t < 256) {
        const int col = t & 127, r = t >> 7;
        float s = bq[col];
        #pragma unroll
        for (int slab = 0; slab < 4; ++slab)
            s += qpart[(slab * 2 + r) * 128 + col];
        qp[r * 128 + col] = s;
    }
    __syncthreads();

    // ---- 4. g[rh][e]: Wk already in registers (R4 mapping) ----
    {
        const float inv_sqrt_ek = 0.17677669529663687f;  // 1/sqrt(32)
        #pragma unroll
        for (int r = 0; r < 2; ++r) {
            const float4* qp4 = reinterpret_cast<const float4*>(qp + r * 128 + p4 * EK_);
            float acc = 0.0f;
            #pragma unroll
            for (int j = 0; j < 8; ++j) {
                float4 pv = qp4[j];
                acc = fmaf(wkr[j].x, pv.x, acc);
                acc = fmaf(wkr[j].y, pv.y, acc);
                acc = fmaf(wkr[j].z, pv.z, acc);
                acc = fmaf(wkr[j].w, pv.w, acc);
            }
            g[(r * 4 + p4) * 128 + e4] = acc * inv_sqrt_ek;
        }
    }
    __syncthreads();   // kt staging long since drained (phase-2 vmcnt waits)

    // ---- 5a. score partials: 2 rows/lane (k5, k5+128) x e-quarter eq5 ----
    const int k5  = t & 127;
    const int eq5 = t >> 7;           // 0..3
    float acc0[8] = {0.f, 0.f, 0.f, 0.f, 0.f, 0.f, 0.f, 0.f};
    float acc1[8] = {0.f, 0.f, 0.f, 0.f, 0.f, 0.f, 0.f, 0.f};
    {
        const int xr = k5 & 7;        // == (k5+128)&7
        const float4* kt4 = reinterpret_cast<const float4*>(kt);
        const float4* g4  = reinterpret_cast<const float4*>(g);
        #pragma unroll
        for (int j = 0; j < 8; ++j) {
            const int jj = eq5 * 8 + j;
            const float4 kv0 = kt4[k5 * 32 + (jj ^ xr)];
            const float4 kv1 = kt4[(k5 + 128) * 32 + (jj ^ xr)];
            #pragma unroll
            for (int rh = 0; rh < 8; ++rh) {
                const float4 gg = g4[rh * 32 + jj];
                acc0[rh] = fmaf(kv0.x, gg.x, acc0[rh]);
                acc0[rh] = fmaf(kv0.y, gg.y, acc0[rh]);
                acc0[rh] = fmaf(kv0.z, gg.z, acc0[rh]);
                acc0[rh] = fmaf(kv0.w, gg.w, acc0[rh]);
                acc1[rh] = fmaf(kv1.x, gg.x, acc1[rh]);
                acc1[rh] = fmaf(kv1.y, gg.y, acc1[rh]);
                acc1[rh] = fmaf(kv1.z, gg.z, acc1[rh]);
                acc1[rh] = fmaf(kv1.w, gg.w, acc1[rh]);
            }
        }
    }
    __syncthreads();                  // kt dead -> spart may alias it

    // ---- 5b. write spart (lanes consecutive k -> conflict-free) ----
    #pragma unroll
    for (int rh = 0; rh < 8; ++rh) {
        spart[(eq5 * 8 + rh) * 256 + k5]       = acc0[rh];
        spart[(eq5 * 8 + rh) * 256 + k5 + 128] = acc1[rh];
    }
    __syncthreads();

    // ---- 6+7. combine 4 e-quarters + max + exp (wave w owns rh=w) ----
    {
        const int w = t >> 6;        // rh
        const int l = t & 63;        // k-quad
        const float4* sp4 = reinterpret_cast<const float4*>(spart);
        float4 s0 = sp4[w * 64 + l];
        #pragma unroll
        for (int eq = 1; eq < 4; ++eq) {
            float4 s1 = sp4[(eq * 8 + w) * 64 + l];
            s0.x += s1.x; s0.y += s1.y; s0.z += s1.z; s0.w += s1.w;
        }
        float m = fmaxf(fmaxf(s0.x, s0.y), fmaxf(s0.z, s0.w));
        #pragma unroll
        for (int off = 32; off; off >>= 1)
            m = fmaxf(m, __shfl_xor(m, off));
        float4 e;
        e.x = __expf(s0.x - m); e.y = __expf(s0.y - m);
        e.z = __expf(s0.z - m); e.w = __expf(s0.w - m);
        *reinterpret_cast<float4*>(&e_lds[w * LK_ + l * 4]) = e;
    }
    __syncthreads();

    // ---- 8. masked num/den over k: f4 e_lds reads (2-way = free) ----
    {
        float num[8] = {0.f, 0.f, 0.f, 0.f, 0.f, 0.f, 0.f, 0.f};
        float den[8] = {0.f, 0.f, 0.f, 0.f, 0.f, 0.f, 0.f, 0.f};
        #pragma unroll
        for (int jq = 0; jq < 4; ++jq) {
            const float4 mv4 = make_float4(mfv[jq*4+0]*vv[jq*4+0], mfv[jq*4+1]*vv[jq*4+1],
                                           mfv[jq*4+2]*vv[jq*4+2], mfv[jq*4+3]*vv[jq*4+3]);
            const float4 mf4 = make_float4(mfv[jq*4+0], mfv[jq*4+1],
                                           mfv[jq*4+2], mfv[jq*4+3]);
            #pragma unroll
            for (int rh = 0; rh < 8; ++rh) {
                float4 ev = *reinterpret_cast<const float4*>(
                    &e_lds[rh * LK_ + kg * 16 + jq * 4]);
                num[rh] = fmaf(ev.x, mv4.x, num[rh]);
                num[rh] = fmaf(ev.y, mv4.y, num[rh]);
                num[rh] = fmaf(ev.z, mv4.z, num[rh]);
                num[rh] = fmaf(ev.w, mv4.w, num[rh]);
                den[rh] = fmaf(ev.x, mf4.x, den[rh]);
                den[rh] = fmaf(ev.y, mf4.y, den[rh]);
                den[rh] = fmaf(ev.z, mf4.z, den[rh]);
                den[rh] = fmaf(ev.w, mf4.w, den[rh]);
            }
        }
        #pragma unroll
        for (int rh = 0; rh < 8; ++rh) {
            nump[(kg * 8 + rh) * 32 + d] = num[rh];
            denp[(kg * 8 + rh) * 32 + d] = den[rh];
        }
    }
    __syncthreads();

    // ---- 9. x = num/den ----
    if (t < 256) {
        const int rh = t >> 5, dd = t & 31;
        float n = 0.f, dn = 0.f;
        #pragma unroll
        for (int k2 = 0; k2 < 16; ++k2) {
            n  += nump[(k2 * 8 + rh) * 32 + dd];
            dn += denp[(k2 * 8 + rh) * 32 + dd];
        }
        x[(rh >> 2) * 128 + (rh & 3) * 32 + dd] = n / dn;
    }
    __syncthreads();

    // ---- 10. out projection, f4 x broadcasts, Wo read once (r inside) ----
    {
        const int col = t & 127;
        const int eq  = t >> 7;      // 0..3
        const int c0  = eq * 32;
        const float* wo = Wo + (size_t)c0 * NH_ + col;
        const float4* x40 = reinterpret_cast<const float4*>(x + c0);
        const float4* x41 = reinterpret_cast<const float4*>(x + 128 + c0);
        float acc0o = 0.f, acc1o = 0.f;
        #pragma unroll
        for (int j = 0; j < 8; ++j) {
            float4 xv0 = x40[j];
            float4 xv1 = x41[j];
            float w0 = wo[(size_t)(j * 4 + 0) * NH_];
            float w1 = wo[(size_t)(j * 4 + 1) * NH_];
            float w2 = wo[(size_t)(j * 4 + 2) * NH_];
            float w3 = wo[(size_t)(j * 4 + 3) * NH_];
            acc0o = fmaf(xv0.x, w0, acc0o); acc1o = fmaf(xv1.x, w0, acc1o);
            acc0o = fmaf(xv0.y, w1, acc0o); acc1o = fmaf(xv1.y, w1, acc1o);
            acc0o = fmaf(xv0.z, w2, acc0o); acc1o = fmaf(xv1.z, w2, acc1o);
            acc0o = fmaf(xv0.w, w3, acc0o); acc1o = fmaf(xv1.w, w3, acc1o);
        }
        opart[(eq * 2 + 0) * 128 + col] = acc0o;
        opart[(eq * 2 + 1) * 128 + col] = acc1o;
    }
    __syncthreads();

    // ---- 11. finalize + store both rows ----
    if (t < 256) {
        const int col = t & 127, r = t >> 7;
        float s = bo[col];
        #pragma unroll
        for (int eq = 0; eq < 4; ++eq)
            s += opart[(eq * 2 + r) * 128 + col];
        out[((size_t)(b * LQ_) + q0 + r) * NH_ + col] = s;
    }
}

extern "C" void kernel_launch(void* const* d_in, const int* in_sizes, int n_in,
                              void* d_out, int out_size, void* d_ws, size_t ws_size,
                              hipStream_t stream) {
    const float* query = (const float*)d_in[0];
    const float* key   = (const float*)d_in[1];
    const float* value = (const float*)d_in[2];
    const int*   mask  = (const int*)d_in[3];
    const float* Wq    = (const float*)d_in[4];
    const float* bq    = (const float*)d_in[5];
    const float* Wk    = (const float*)d_in[6];
    // d_in[7] = bk: k-constant in scores -> cancels in softmax -> unused
    const float* Wo    = (const float*)d_in[8];
    const float* bo    = (const float*)d_in[9];
    float* out = (float*)d_out;

    const size_t lds_bytes = 35328 * sizeof(float);   // 138 KB
    static bool attr_set = false;
    if (!attr_set) {
        hipFuncSetAttribute(reinterpret_cast<const void*>(fused_attn_kernel),
                            hipFuncAttributeMaxDynamicSharedMemorySize,
                            (int)lds_bytes);
        attr_set = true;
    }

    fused_attn_kernel<<<B_ * (LQ_ / 2), 512, lds_bytes, stream>>>(
        query, key, value, mask, Wq, bq, Wk, Wo, bo, out);
}